// Round 4
// baseline (363.579 us; speedup 1.0000x reference)
//
#include <hip/hip_runtime.h>

// GraphSAGE 2-layer, N=50000, E=800000, D=128.
// R4: XCD-sharded aggregation — block b handles feature chunk (b&7) so each
// XCD's gather working set (1/8 feature slice of x, ~3.2MB) fits its private
// 4MB L2. Gather moves from L3-bound (~3TB/s) to L2-resident.
// Rest unchanged from R3 (counting-sort CSR, MFMA dual-GEMM).

#define D 128
#define NBITS 7
#define BNODES 128   // nodes per bucket
#define GA 64        // phase A/B block count
#define NPG 16       // nodes per group in sharded aggregate
typedef unsigned short u16;
typedef unsigned u32;
typedef short bf16x8 __attribute__((ext_vector_type(8)));
typedef float f32x4 __attribute__((ext_vector_type(4)));

__device__ __forceinline__ u16 f2bf(float f) {
    union { float f; unsigned u; } x;
    x.f = f;
    unsigned r = x.u + 0x7FFF + ((x.u >> 16) & 1);  // RNE
    return (u16)(r >> 16);
}
__device__ __forceinline__ float bf2f(u16 b) {
    union { unsigned u; float f; } x;
    x.u = ((unsigned)b) << 16;
    return x.f;
}

// ---------------- CSR build: two-level counting sort ----------------

__global__ __launch_bounds__(1024) void bucket_hist(const int* __restrict__ dst,
                                                    int* __restrict__ Gcounts,
                                                    int E, int NB, int chunk) {
    __shared__ int cnt[512];
    for (int i = threadIdx.x; i < NB; i += 1024) cnt[i] = 0;
    __syncthreads();
    int base = blockIdx.x * chunk;
    int end = base + chunk; if (end > E) end = E;
    for (int e = base + threadIdx.x; e < end; e += 1024)
        atomicAdd(&cnt[dst[e] >> NBITS], 1);
    __syncthreads();
    for (int b = threadIdx.x; b < NB; b += 1024)
        Gcounts[b * GA + blockIdx.x] = cnt[b];
}

__global__ __launch_bounds__(1024) void scan1_kernel(const int* __restrict__ in,
                                                     int* __restrict__ excl,
                                                     int* __restrict__ totals, int n) {
    int chunk = blockIdx.x;
    int i = chunk * 1024 + threadIdx.x;
    int v = (i < n) ? in[i] : 0;
    int lane = threadIdx.x & 63;
    int wid = threadIdx.x >> 6;
    int s = v;
    #pragma unroll
    for (int off = 1; off < 64; off <<= 1) {
        int t = __shfl_up(s, off);
        if (lane >= off) s += t;
    }
    __shared__ int wsum[16];
    if (lane == 63) wsum[wid] = s;
    __syncthreads();
    if (wid == 0) {
        int ws = (lane < 16) ? wsum[lane] : 0;
        #pragma unroll
        for (int off = 1; off < 16; off <<= 1) {
            int t = __shfl_up(ws, off);
            if (lane >= off) ws += t;
        }
        if (lane < 16) wsum[lane] = ws;
    }
    __syncthreads();
    int wave_off = (wid > 0) ? wsum[wid - 1] : 0;
    int incl = s + wave_off;
    if (i < n) excl[i] = incl - v;
    if (threadIdx.x == 1023) totals[chunk] = incl;
}

__global__ __launch_bounds__(1024) void scan_add(int* __restrict__ Sc,
                                                 const int* __restrict__ totals, int n) {
    int chunk = blockIdx.x;
    int i = chunk * 1024 + threadIdx.x;
    int off = 0;
    for (int j = 0; j < chunk; ++j) off += totals[j];
    if (i < n) Sc[i] += off;
}

__global__ __launch_bounds__(1024) void bucket_scatter(const int* __restrict__ src,
                                                       const int* __restrict__ dst,
                                                       const int* __restrict__ Sc,
                                                       u32* __restrict__ Ebuck,
                                                       int E, int NB, int chunk) {
    __shared__ int cur[512];
    for (int b = threadIdx.x; b < NB; b += 1024) cur[b] = Sc[b * GA + blockIdx.x];
    __syncthreads();
    int base = blockIdx.x * chunk;
    int end = base + chunk; if (end > E) end = E;
    for (int e = base + threadIdx.x; e < end; e += 1024) {
        int d = dst[e];
        int b = d >> NBITS;
        int pos = atomicAdd(&cur[b], 1);
        Ebuck[pos] = ((u32)(d & (BNODES - 1)) << 16) | (u32)src[e];
    }
}

__global__ __launch_bounds__(256) void bucket_sort_csr(u32* __restrict__ Ebuck,
                                                       const int* __restrict__ Sc,
                                                       int* __restrict__ row_ptr,
                                                       int E, int N, int NB) {
    __shared__ int hist[BNODES], excl[BNODES], cur[BNODES];
    __shared__ u16 sorted[8192];
    int b = blockIdx.x;
    int start = Sc[b * GA];
    int endv = (b + 1 < NB) ? Sc[(b + 1) * GA] : E;
    int cnt = endv - start;
    if (cnt > 8192) cnt = 8192;
    for (int i = threadIdx.x; i < BNODES; i += 256) hist[i] = 0;
    __syncthreads();
    for (int i = threadIdx.x; i < cnt; i += 256)
        atomicAdd(&hist[Ebuck[start + i] >> 16], 1);
    __syncthreads();
    if (threadIdx.x == 0) {
        int run = 0;
        for (int i = 0; i < BNODES; ++i) { excl[i] = run; run += hist[i]; }
    }
    __syncthreads();
    for (int i = threadIdx.x; i < BNODES; i += 256) {
        cur[i] = excl[i];
        int g = b * BNODES + i;
        if (g <= N) row_ptr[g] = start + excl[i];
    }
    __syncthreads();
    for (int i = threadIdx.x; i < cnt; i += 256) {
        u32 r = Ebuck[start + i];
        int pos = atomicAdd(&cur[r >> 16], 1);
        sorted[pos] = (u16)(r & 0xFFFF);
    }
    __syncthreads();
    for (int i = threadIdx.x; i < cnt; i += 256)
        ((int*)Ebuck)[start + i] = (int)sorted[i];   // csr == Ebuck alias
}

// ---------------- fp32 -> bf16 converts ----------------
__global__ void f32_to_bf16_kernel(const float* __restrict__ in, u16* __restrict__ out, int n4) {
    int i = blockIdx.x * 256 + threadIdx.x;
    if (i < n4) {
        float4 v = *(const float4*)&in[i * 4];
        ushort4 o;
        o.x = f2bf(v.x); o.y = f2bf(v.y); o.z = f2bf(v.z); o.w = f2bf(v.w);
        *(ushort4*)&out[i * 4] = o;
    }
}

__global__ void convert_weights(const float* __restrict__ w0, const float* __restrict__ w1,
                                const float* __restrict__ w2, const float* __restrict__ w3,
                                u16* __restrict__ o0, u16* __restrict__ o1,
                                u16* __restrict__ o2, u16* __restrict__ o3) {
    int i = blockIdx.x * 256 + threadIdx.x;
    const int q = D * D / 4;  // 4096
    int m = i / q, j = i % q;
    const float* in = (m == 0) ? w0 : (m == 1) ? w1 : (m == 2) ? w2 : w3;
    u16* out = (m == 0) ? o0 : (m == 1) ? o1 : (m == 2) ? o2 : o3;
    float4 v = *(const float4*)&in[j * 4];
    ushort4 o;
    o.x = f2bf(v.x); o.y = f2bf(v.y); o.z = f2bf(v.z); o.w = f2bf(v.w);
    *(ushort4*)&out[j * 4] = o;
}

// ---------------- XCD-sharded mean aggregation ----------------
// Block b: feature chunk c = b&7 (rides blockIdx%8 -> XCD round-robin), node
// group g = b>>3 (NPG nodes). Each XCD touches only its 16-feature slice of
// xb (~3.2MB incl. line waste) -> L2-resident gather.
// Wave: lane = edge_slot(8)*8 + feat_pair(8); 8 edges in flight, unroll x2;
// shfl_xor(8/16/32) reduces over edge slots; lanes 0..7 store 32B slice.
__global__ __launch_bounds__(256) void aggregate_sharded(const u16* __restrict__ xb,
                                                         const int* __restrict__ row_ptr,
                                                         const int* __restrict__ csr,
                                                         u16* __restrict__ aggb, int n) {
    const int chunk = blockIdx.x & 7;
    const int grp = blockIdx.x >> 3;
    const int wave = threadIdx.x >> 6;
    const int lane = threadIdx.x & 63;
    const int g = lane >> 3;        // edge slot
    const int f = lane & 7;         // feature pair
    const int cbase = chunk * 16 + f * 2;

    #pragma unroll
    for (int i = 0; i < NPG / 4; ++i) {
        int node = grp * NPG + wave * (NPG / 4) + i;
        if (node >= n) return;
        int begin = row_ptr[node], end = row_ptr[node + 1];
        float a0 = 0.f, a1 = 0.f;
        int j = begin + g;
        for (; j + 8 < end; j += 16) {   // 16 edges per iter (2 per slot)
            int s0 = csr[j], s1 = csr[j + 8];
            u32 v0 = *(const u32*)&xb[s0 * D + cbase];
            u32 v1 = *(const u32*)&xb[s1 * D + cbase];
            a0 += bf2f((u16)(v0 & 0xFFFF)) + bf2f((u16)(v1 & 0xFFFF));
            a1 += bf2f((u16)(v0 >> 16)) + bf2f((u16)(v1 >> 16));
        }
        if (j < end) {
            int s0 = csr[j];
            u32 v0 = *(const u32*)&xb[s0 * D + cbase];
            a0 += bf2f((u16)(v0 & 0xFFFF));
            a1 += bf2f((u16)(v0 >> 16));
        }
        a0 += __shfl_xor(a0, 8);  a1 += __shfl_xor(a1, 8);
        a0 += __shfl_xor(a0, 16); a1 += __shfl_xor(a1, 16);
        a0 += __shfl_xor(a0, 32); a1 += __shfl_xor(a1, 32);
        if (g == 0) {
            int d = end - begin;
            if (d < 1) d = 1;
            float inv = 1.0f / (float)d;
            u32 o = ((u32)f2bf(a1 * inv) << 16) | (u32)f2bf(a0 * inv);
            *(u32*)&aggb[node * D + cbase] = o;
        }
    }
}

// ---------------- dual-GEMM via MFMA ----------------
#define LSTR 136

__global__ __launch_bounds__(256) void gemm_mfma(const u16* __restrict__ Aroot,
                                                 const u16* __restrict__ Wr,
                                                 const u16* __restrict__ Agg,
                                                 const u16* __restrict__ Wl,
                                                 const float* __restrict__ bias,
                                                 void* __restrict__ out,
                                                 int n, int mode) {  // mode1: relu+bf16 out
    __shared__ __align__(16) u16 Lr[64 * LSTR];
    __shared__ __align__(16) u16 Lg[64 * LSTR];
    const int tid = threadIdx.x;
    const int n0 = blockIdx.x * 64;

    {
        int row = tid >> 4;
        int c = (tid & 15) * 8;
        #pragma unroll
        for (int p = 0; p < 4; ++p) {
            int r = p * 16 + row;
            int g = n0 + r;
            float4 vr = make_float4(0.f, 0.f, 0.f, 0.f);
            float4 vg = make_float4(0.f, 0.f, 0.f, 0.f);
            if (g < n) {
                vr = *(const float4*)&Aroot[g * D + c];
                vg = *(const float4*)&Agg[g * D + c];
            }
            *(float4*)&Lr[r * LSTR + c] = vr;
            *(float4*)&Lg[r * LSTR + c] = vg;
        }
    }

    const int wave = tid >> 6;
    const int lane = tid & 63;
    const int quad = lane >> 4;
    const int l16 = lane & 15;

    bf16x8 wr[2][4], wl[2][4];
    #pragma unroll
    for (int mt = 0; mt < 2; ++mt) {
        int jrow = wave * 32 + mt * 16 + l16;
        #pragma unroll
        for (int kb = 0; kb < 4; ++kb) {
            wr[mt][kb] = *(const bf16x8*)&Wr[jrow * D + kb * 32 + quad * 8];
            wl[mt][kb] = *(const bf16x8*)&Wl[jrow * D + kb * 32 + quad * 8];
        }
    }

    __syncthreads();

    f32x4 acc[4][2];
    #pragma unroll
    for (int it = 0; it < 4; ++it)
        #pragma unroll
        for (int mt = 0; mt < 2; ++mt)
            acc[it][mt] = (f32x4){0.f, 0.f, 0.f, 0.f};

    #pragma unroll
    for (int it = 0; it < 4; ++it) {
        int base = (it * 16 + l16) * LSTR + quad * 8;
        #pragma unroll
        for (int kb = 0; kb < 4; ++kb) {
            bf16x8 bx = *(const bf16x8*)&Lr[base + kb * 32];
            bf16x8 bg = *(const bf16x8*)&Lg[base + kb * 32];
            #pragma unroll
            for (int mt = 0; mt < 2; ++mt) {
                acc[it][mt] = __builtin_amdgcn_mfma_f32_16x16x32_bf16(wr[mt][kb], bx, acc[it][mt], 0, 0, 0);
                acc[it][mt] = __builtin_amdgcn_mfma_f32_16x16x32_bf16(wl[mt][kb], bg, acc[it][mt], 0, 0, 0);
            }
        }
    }

    #pragma unroll
    for (int it = 0; it < 4; ++it) {
        int i = n0 + it * 16 + l16;
        if (i < n) {
            #pragma unroll
            for (int mt = 0; mt < 2; ++mt) {
                int j0 = wave * 32 + mt * 16 + quad * 4;
                float4 bv = *(const float4*)&bias[j0];
                float o0 = acc[it][mt][0] + bv.x;
                float o1 = acc[it][mt][1] + bv.y;
                float o2 = acc[it][mt][2] + bv.z;
                float o3 = acc[it][mt][3] + bv.w;
                if (mode) {
                    o0 = fmaxf(o0, 0.f); o1 = fmaxf(o1, 0.f);
                    o2 = fmaxf(o2, 0.f); o3 = fmaxf(o3, 0.f);
                    ushort4 ob;
                    ob.x = f2bf(o0); ob.y = f2bf(o1); ob.z = f2bf(o2); ob.w = f2bf(o3);
                    *(ushort4*)&((u16*)out)[i * D + j0] = ob;
                } else {
                    float4 of = make_float4(o0, o1, o2, o3);
                    *(float4*)&((float*)out)[i * D + j0] = of;
                }
            }
        }
    }
}

// ---------------- launch ----------------

extern "C" void kernel_launch(void* const* d_in, const int* in_sizes, int n_in,
                              void* d_out, int out_size, void* d_ws, size_t ws_size,
                              hipStream_t stream) {
    const float* x = (const float*)d_in[0];
    const int* edge = (const int*)d_in[1];
    const float* Wl0 = (const float*)d_in[2];
    const float* Wr0 = (const float*)d_in[3];
    const float* b0 = (const float*)d_in[4];
    const float* Wl1 = (const float*)d_in[5];
    const float* Wr1 = (const float*)d_in[6];
    const float* b1 = (const float*)d_in[7];

    const int N = in_sizes[0] / D;
    const int E = in_sizes[1] / 2;
    const int* src = edge;
    const int* dst = edge + E;

    char* ws = (char*)d_ws;
    size_t off = 0;
    auto alloc = [&](size_t bytes) {
        char* p = ws + off;
        off += (bytes + 255) & ~(size_t)255;
        return p;
    };
    int* row_ptr = (int*)alloc((size_t)(N + 1) * 4);
    u32* Ebuck = (u32*)alloc((size_t)E * 4);          // becomes csr in-place
    u16* xb = (u16*)alloc((size_t)N * D * 2);
    u16* hb = (u16*)alloc((size_t)N * D * 2);
    u16* aggb = (u16*)alloc((size_t)N * D * 2);
    u16* Wl0b = (u16*)alloc((size_t)D * D * 2);
    u16* Wr0b = (u16*)alloc((size_t)D * D * 2);
    u16* Wl1b = (u16*)alloc((size_t)D * D * 2);
    u16* Wr1b = (u16*)alloc((size_t)D * D * 2);
    const int NB = (N + BNODES - 1) / BNODES;
    const int scanN = NB * GA;
    int* Gcounts = (int*)aggb;   // scan scratch overlaps aggb (dead until agg)
    int* Sc = Gcounts + scanN;
    int* totals = Sc + scanN;

    (void)ws_size; (void)n_in; (void)out_size;

    const int chunk = (E + GA - 1) / GA;
    const int scanBlocks = (scanN + 1023) / 1024;

    // CSR build
    bucket_hist<<<GA, 1024, 0, stream>>>(dst, Gcounts, E, NB, chunk);
    scan1_kernel<<<scanBlocks, 1024, 0, stream>>>(Gcounts, Sc, totals, scanN);
    scan_add<<<scanBlocks, 1024, 0, stream>>>(Sc, totals, scanN);
    bucket_scatter<<<GA, 1024, 0, stream>>>(src, dst, Sc, Ebuck, E, NB, chunk);
    bucket_sort_csr<<<NB, 256, 0, stream>>>(Ebuck, Sc, row_ptr, E, N, NB);
    const int* csr = (const int*)Ebuck;

    // converts
    int xQuads = N * D / 4;
    f32_to_bf16_kernel<<<(xQuads + 255) / 256, 256, 0, stream>>>(x, xb, xQuads);
    convert_weights<<<(4 * D * D / 4 + 255) / 256, 256, 0, stream>>>(
        Wl0, Wr0, Wl1, Wr1, Wl0b, Wr0b, Wl1b, Wr1b);

    int aggBlocks = 8 * ((N + NPG - 1) / NPG);
    int gemmBlocks = (N + 63) / 64;

    // layer 0
    aggregate_sharded<<<aggBlocks, 256, 0, stream>>>(xb, row_ptr, csr, aggb, N);
    gemm_mfma<<<gemmBlocks, 256, 0, stream>>>(xb, Wr0b, aggb, Wl0b, b0, hb, N, 1);
    // layer 1
    aggregate_sharded<<<aggBlocks, 256, 0, stream>>>(hb, row_ptr, csr, aggb, N);
    gemm_mfma<<<gemmBlocks, 256, 0, stream>>>(hb, Wr1b, aggb, Wl1b, b1, d_out, N, 0);
}

// Round 6
// 307.263 us; speedup vs baseline: 1.1833x; 1.1833x over previous
//
#include <hip/hip_runtime.h>

// GraphSAGE 2-layer, N=50000, E=800000, D=128.
// R6 (= R5 + compile fix): XCD-sharded aggregation.
//  - 4 chunks x 32 features = 64B-aligned slice (1 line/row-visit, no cross-XCD
//    line sharing; worst-case traffic == R3).
//  - chunk = blockIdx&3; with blockIdx%8->XCD round-robin each XCD serves one
//    chunk (footprint 3.2MB < 4MB L2).
//  - csr reads + aggb writes non-temporal (u64-packed store) so the x-slice
//    stays L2-resident.
// Rest unchanged (counting-sort CSR, MFMA dual-GEMM).

#define D 128
#define NBITS 7
#define BNODES 128   // nodes per bucket
#define GA 64        // phase A/B block count
#define NPG 16       // nodes per block in sharded aggregate
typedef unsigned short u16;
typedef unsigned u32;
typedef unsigned long long u64;
typedef short bf16x8 __attribute__((ext_vector_type(8)));
typedef float f32x4 __attribute__((ext_vector_type(4)));

__device__ __forceinline__ u16 f2bf(float f) {
    union { float f; unsigned u; } x;
    x.f = f;
    unsigned r = x.u + 0x7FFF + ((x.u >> 16) & 1);  // RNE
    return (u16)(r >> 16);
}
__device__ __forceinline__ float bf2f(u16 b) {
    union { unsigned u; float f; } x;
    x.u = ((unsigned)b) << 16;
    return x.f;
}

// ---------------- CSR build: two-level counting sort ----------------

__global__ __launch_bounds__(1024) void bucket_hist(const int* __restrict__ dst,
                                                    int* __restrict__ Gcounts,
                                                    int E, int NB, int chunk) {
    __shared__ int cnt[512];
    for (int i = threadIdx.x; i < NB; i += 1024) cnt[i] = 0;
    __syncthreads();
    int base = blockIdx.x * chunk;
    int end = base + chunk; if (end > E) end = E;
    for (int e = base + threadIdx.x; e < end; e += 1024)
        atomicAdd(&cnt[dst[e] >> NBITS], 1);
    __syncthreads();
    for (int b = threadIdx.x; b < NB; b += 1024)
        Gcounts[b * GA + blockIdx.x] = cnt[b];
}

__global__ __launch_bounds__(1024) void scan1_kernel(const int* __restrict__ in,
                                                     int* __restrict__ excl,
                                                     int* __restrict__ totals, int n) {
    int chunk = blockIdx.x;
    int i = chunk * 1024 + threadIdx.x;
    int v = (i < n) ? in[i] : 0;
    int lane = threadIdx.x & 63;
    int wid = threadIdx.x >> 6;
    int s = v;
    #pragma unroll
    for (int off = 1; off < 64; off <<= 1) {
        int t = __shfl_up(s, off);
        if (lane >= off) s += t;
    }
    __shared__ int wsum[16];
    if (lane == 63) wsum[wid] = s;
    __syncthreads();
    if (wid == 0) {
        int ws = (lane < 16) ? wsum[lane] : 0;
        #pragma unroll
        for (int off = 1; off < 16; off <<= 1) {
            int t = __shfl_up(ws, off);
            if (lane >= off) ws += t;
        }
        if (lane < 16) wsum[lane] = ws;
    }
    __syncthreads();
    int wave_off = (wid > 0) ? wsum[wid - 1] : 0;
    int incl = s + wave_off;
    if (i < n) excl[i] = incl - v;
    if (threadIdx.x == 1023) totals[chunk] = incl;
}

__global__ __launch_bounds__(1024) void scan_add(int* __restrict__ Sc,
                                                 const int* __restrict__ totals, int n) {
    int chunk = blockIdx.x;
    int i = chunk * 1024 + threadIdx.x;
    int off = 0;
    for (int j = 0; j < chunk; ++j) off += totals[j];
    if (i < n) Sc[i] += off;
}

__global__ __launch_bounds__(1024) void bucket_scatter(const int* __restrict__ src,
                                                       const int* __restrict__ dst,
                                                       const int* __restrict__ Sc,
                                                       u32* __restrict__ Ebuck,
                                                       int E, int NB, int chunk) {
    __shared__ int cur[512];
    for (int b = threadIdx.x; b < NB; b += 1024) cur[b] = Sc[b * GA + blockIdx.x];
    __syncthreads();
    int base = blockIdx.x * chunk;
    int end = base + chunk; if (end > E) end = E;
    for (int e = base + threadIdx.x; e < end; e += 1024) {
        int d = dst[e];
        int b = d >> NBITS;
        int pos = atomicAdd(&cur[b], 1);
        Ebuck[pos] = ((u32)(d & (BNODES - 1)) << 16) | (u32)src[e];
    }
}

__global__ __launch_bounds__(256) void bucket_sort_csr(u32* __restrict__ Ebuck,
                                                       const int* __restrict__ Sc,
                                                       int* __restrict__ row_ptr,
                                                       int E, int N, int NB) {
    __shared__ int hist[BNODES], excl[BNODES], cur[BNODES];
    __shared__ u16 sorted[8192];
    int b = blockIdx.x;
    int start = Sc[b * GA];
    int endv = (b + 1 < NB) ? Sc[(b + 1) * GA] : E;
    int cnt = endv - start;
    if (cnt > 8192) cnt = 8192;
    for (int i = threadIdx.x; i < BNODES; i += 256) hist[i] = 0;
    __syncthreads();
    for (int i = threadIdx.x; i < cnt; i += 256)
        atomicAdd(&hist[Ebuck[start + i] >> 16], 1);
    __syncthreads();
    if (threadIdx.x == 0) {
        int run = 0;
        for (int i = 0; i < BNODES; ++i) { excl[i] = run; run += hist[i]; }
    }
    __syncthreads();
    for (int i = threadIdx.x; i < BNODES; i += 256) {
        cur[i] = excl[i];
        int g = b * BNODES + i;
        if (g <= N) row_ptr[g] = start + excl[i];
    }
    __syncthreads();
    for (int i = threadIdx.x; i < cnt; i += 256) {
        u32 r = Ebuck[start + i];
        int pos = atomicAdd(&cur[r >> 16], 1);
        sorted[pos] = (u16)(r & 0xFFFF);
    }
    __syncthreads();
    for (int i = threadIdx.x; i < cnt; i += 256)
        ((int*)Ebuck)[start + i] = (int)sorted[i];   // csr == Ebuck alias
}

// ---------------- fp32 -> bf16 converts ----------------
__global__ void f32_to_bf16_kernel(const float* __restrict__ in, u16* __restrict__ out, int n4) {
    int i = blockIdx.x * 256 + threadIdx.x;
    if (i < n4) {
        float4 v = *(const float4*)&in[i * 4];
        ushort4 o;
        o.x = f2bf(v.x); o.y = f2bf(v.y); o.z = f2bf(v.z); o.w = f2bf(v.w);
        *(ushort4*)&out[i * 4] = o;
    }
}

__global__ void convert_weights(const float* __restrict__ w0, const float* __restrict__ w1,
                                const float* __restrict__ w2, const float* __restrict__ w3,
                                u16* __restrict__ o0, u16* __restrict__ o1,
                                u16* __restrict__ o2, u16* __restrict__ o3) {
    int i = blockIdx.x * 256 + threadIdx.x;
    const int q = D * D / 4;  // 4096
    int m = i / q, j = i % q;
    const float* in = (m == 0) ? w0 : (m == 1) ? w1 : (m == 2) ? w2 : w3;
    u16* out = (m == 0) ? o0 : (m == 1) ? o1 : (m == 2) ? o2 : o3;
    float4 v = *(const float4*)&in[j * 4];
    ushort4 o;
    o.x = f2bf(v.x); o.y = f2bf(v.y); o.z = f2bf(v.z); o.w = f2bf(v.w);
    *(ushort4*)&out[j * 4] = o;
}

// ---------------- XCD-sharded mean aggregation (64B slices, nt streams) -----
__global__ __launch_bounds__(256) void aggregate_sharded(const u16* __restrict__ xb,
                                                         const int* __restrict__ row_ptr,
                                                         const int* __restrict__ csr,
                                                         u16* __restrict__ aggb, int n) {
    const int chunk = blockIdx.x & 3;
    const int grp = blockIdx.x >> 2;
    const int wave = threadIdx.x >> 6;
    const int lane = threadIdx.x & 63;
    const int g = lane >> 3;               // edge slot 0..7
    const int f = lane & 7;                // feature quad 0..7
    const int cbase = chunk * 32 + f * 4;  // feature index (8B aligned)

    #pragma unroll
    for (int i = 0; i < NPG / 4; ++i) {
        int node = grp * NPG + wave * (NPG / 4) + i;
        if (node >= n) return;
        int begin = row_ptr[node], end = row_ptr[node + 1];
        float a0 = 0.f, a1 = 0.f, a2 = 0.f, a3 = 0.f;
        int j = begin + g;
        for (; j + 8 < end; j += 16) {   // 16 edges per round (2 per slot)
            int s0 = __builtin_nontemporal_load(&csr[j]);
            int s1 = __builtin_nontemporal_load(&csr[j + 8]);
            ushort4 v0 = *(const ushort4*)&xb[s0 * D + cbase];
            ushort4 v1 = *(const ushort4*)&xb[s1 * D + cbase];
            a0 += bf2f(v0.x) + bf2f(v1.x);
            a1 += bf2f(v0.y) + bf2f(v1.y);
            a2 += bf2f(v0.z) + bf2f(v1.z);
            a3 += bf2f(v0.w) + bf2f(v1.w);
        }
        if (j < end) {
            int s0 = __builtin_nontemporal_load(&csr[j]);
            ushort4 v0 = *(const ushort4*)&xb[s0 * D + cbase];
            a0 += bf2f(v0.x); a1 += bf2f(v0.y); a2 += bf2f(v0.z); a3 += bf2f(v0.w);
        }
        a0 += __shfl_xor(a0, 8);  a1 += __shfl_xor(a1, 8);
        a2 += __shfl_xor(a2, 8);  a3 += __shfl_xor(a3, 8);
        a0 += __shfl_xor(a0, 16); a1 += __shfl_xor(a1, 16);
        a2 += __shfl_xor(a2, 16); a3 += __shfl_xor(a3, 16);
        a0 += __shfl_xor(a0, 32); a1 += __shfl_xor(a1, 32);
        a2 += __shfl_xor(a2, 32); a3 += __shfl_xor(a3, 32);
        if (g == 0) {
            int d = end - begin;
            if (d < 1) d = 1;
            float inv = 1.0f / (float)d;
            u64 o = (u64)f2bf(a0 * inv)
                  | ((u64)f2bf(a1 * inv) << 16)
                  | ((u64)f2bf(a2 * inv) << 32)
                  | ((u64)f2bf(a3 * inv) << 48);
            __builtin_nontemporal_store(o, (u64*)&aggb[node * D + cbase]);
        }
    }
}

// ---------------- dual-GEMM via MFMA ----------------
#define LSTR 136

__global__ __launch_bounds__(256) void gemm_mfma(const u16* __restrict__ Aroot,
                                                 const u16* __restrict__ Wr,
                                                 const u16* __restrict__ Agg,
                                                 const u16* __restrict__ Wl,
                                                 const float* __restrict__ bias,
                                                 void* __restrict__ out,
                                                 int n, int mode) {  // mode1: relu+bf16 out
    __shared__ __align__(16) u16 Lr[64 * LSTR];
    __shared__ __align__(16) u16 Lg[64 * LSTR];
    const int tid = threadIdx.x;
    const int n0 = blockIdx.x * 64;

    {
        int row = tid >> 4;
        int c = (tid & 15) * 8;
        #pragma unroll
        for (int p = 0; p < 4; ++p) {
            int r = p * 16 + row;
            int g = n0 + r;
            float4 vr = make_float4(0.f, 0.f, 0.f, 0.f);
            float4 vg = make_float4(0.f, 0.f, 0.f, 0.f);
            if (g < n) {
                vr = *(const float4*)&Aroot[g * D + c];
                vg = *(const float4*)&Agg[g * D + c];
            }
            *(float4*)&Lr[r * LSTR + c] = vr;
            *(float4*)&Lg[r * LSTR + c] = vg;
        }
    }

    const int wave = tid >> 6;
    const int lane = tid & 63;
    const int quad = lane >> 4;
    const int l16 = lane & 15;

    bf16x8 wr[2][4], wl[2][4];
    #pragma unroll
    for (int mt = 0; mt < 2; ++mt) {
        int jrow = wave * 32 + mt * 16 + l16;
        #pragma unroll
        for (int kb = 0; kb < 4; ++kb) {
            wr[mt][kb] = *(const bf16x8*)&Wr[jrow * D + kb * 32 + quad * 8];
            wl[mt][kb] = *(const bf16x8*)&Wl[jrow * D + kb * 32 + quad * 8];
        }
    }

    __syncthreads();

    f32x4 acc[4][2];
    #pragma unroll
    for (int it = 0; it < 4; ++it)
        #pragma unroll
        for (int mt = 0; mt < 2; ++mt)
            acc[it][mt] = (f32x4){0.f, 0.f, 0.f, 0.f};

    #pragma unroll
    for (int it = 0; it < 4; ++it) {
        int base = (it * 16 + l16) * LSTR + quad * 8;
        #pragma unroll
        for (int kb = 0; kb < 4; ++kb) {
            bf16x8 bx = *(const bf16x8*)&Lr[base + kb * 32];
            bf16x8 bg = *(const bf16x8*)&Lg[base + kb * 32];
            #pragma unroll
            for (int mt = 0; mt < 2; ++mt) {
                acc[it][mt] = __builtin_amdgcn_mfma_f32_16x16x32_bf16(wr[mt][kb], bx, acc[it][mt], 0, 0, 0);
                acc[it][mt] = __builtin_amdgcn_mfma_f32_16x16x32_bf16(wl[mt][kb], bg, acc[it][mt], 0, 0, 0);
            }
        }
    }

    #pragma unroll
    for (int it = 0; it < 4; ++it) {
        int i = n0 + it * 16 + l16;
        if (i < n) {
            #pragma unroll
            for (int mt = 0; mt < 2; ++mt) {
                int j0 = wave * 32 + mt * 16 + quad * 4;
                float4 bv = *(const float4*)&bias[j0];
                float o0 = acc[it][mt][0] + bv.x;
                float o1 = acc[it][mt][1] + bv.y;
                float o2 = acc[it][mt][2] + bv.z;
                float o3 = acc[it][mt][3] + bv.w;
                if (mode) {
                    o0 = fmaxf(o0, 0.f); o1 = fmaxf(o1, 0.f);
                    o2 = fmaxf(o2, 0.f); o3 = fmaxf(o3, 0.f);
                    ushort4 ob;
                    ob.x = f2bf(o0); ob.y = f2bf(o1); ob.z = f2bf(o2); ob.w = f2bf(o3);
                    *(ushort4*)&((u16*)out)[i * D + j0] = ob;
                } else {
                    float4 of = make_float4(o0, o1, o2, o3);
                    *(float4*)&((float*)out)[i * D + j0] = of;
                }
            }
        }
    }
}

// ---------------- launch ----------------

extern "C" void kernel_launch(void* const* d_in, const int* in_sizes, int n_in,
                              void* d_out, int out_size, void* d_ws, size_t ws_size,
                              hipStream_t stream) {
    const float* x = (const float*)d_in[0];
    const int* edge = (const int*)d_in[1];
    const float* Wl0 = (const float*)d_in[2];
    const float* Wr0 = (const float*)d_in[3];
    const float* b0 = (const float*)d_in[4];
    const float* Wl1 = (const float*)d_in[5];
    const float* Wr1 = (const float*)d_in[6];
    const float* b1 = (const float*)d_in[7];

    const int N = in_sizes[0] / D;
    const int E = in_sizes[1] / 2;
    const int* src = edge;
    const int* dst = edge + E;

    char* ws = (char*)d_ws;
    size_t off = 0;
    auto alloc = [&](size_t bytes) {
        char* p = ws + off;
        off += (bytes + 255) & ~(size_t)255;
        return p;
    };
    int* row_ptr = (int*)alloc((size_t)(N + 1) * 4);
    u32* Ebuck = (u32*)alloc((size_t)E * 4);          // becomes csr in-place
    u16* xb = (u16*)alloc((size_t)N * D * 2);
    u16* hb = (u16*)alloc((size_t)N * D * 2);
    u16* aggb = (u16*)alloc((size_t)N * D * 2);
    u16* Wl0b = (u16*)alloc((size_t)D * D * 2);
    u16* Wr0b = (u16*)alloc((size_t)D * D * 2);
    u16* Wl1b = (u16*)alloc((size_t)D * D * 2);
    u16* Wr1b = (u16*)alloc((size_t)D * D * 2);
    const int NB = (N + BNODES - 1) / BNODES;
    const int scanN = NB * GA;
    int* Gcounts = (int*)aggb;   // scan scratch overlaps aggb (dead until agg)
    int* Sc = Gcounts + scanN;
    int* totals = Sc + scanN;

    (void)ws_size; (void)n_in; (void)out_size;

    const int chunk = (E + GA - 1) / GA;
    const int scanBlocks = (scanN + 1023) / 1024;

    // CSR build
    bucket_hist<<<GA, 1024, 0, stream>>>(dst, Gcounts, E, NB, chunk);
    scan1_kernel<<<scanBlocks, 1024, 0, stream>>>(Gcounts, Sc, totals, scanN);
    scan_add<<<scanBlocks, 1024, 0, stream>>>(Sc, totals, scanN);
    bucket_scatter<<<GA, 1024, 0, stream>>>(src, dst, Sc, Ebuck, E, NB, chunk);
    bucket_sort_csr<<<NB, 256, 0, stream>>>(Ebuck, Sc, row_ptr, E, N, NB);
    const int* csr = (const int*)Ebuck;

    // converts
    int xQuads = N * D / 4;
    f32_to_bf16_kernel<<<(xQuads + 255) / 256, 256, 0, stream>>>(x, xb, xQuads);
    convert_weights<<<(4 * D * D / 4 + 255) / 256, 256, 0, stream>>>(
        Wl0, Wr0, Wl1, Wr1, Wl0b, Wr0b, Wl1b, Wr1b);

    int aggBlocks = 4 * ((N + NPG - 1) / NPG);
    int gemmBlocks = (N + 63) / 64;

    // layer 0
    aggregate_sharded<<<aggBlocks, 256, 0, stream>>>(xb, row_ptr, csr, aggb, N);
    gemm_mfma<<<gemmBlocks, 256, 0, stream>>>(xb, Wr0b, aggb, Wl0b, b0, hb, N, 1);
    // layer 1
    aggregate_sharded<<<aggBlocks, 256, 0, stream>>>(hb, row_ptr, csr, aggb, N);
    gemm_mfma<<<gemmBlocks, 256, 0, stream>>>(hb, Wr1b, aggb, Wl1b, b1, d_out, N, 0);
}

// Round 7
// 289.114 us; speedup vs baseline: 1.2576x; 1.0628x over previous
//
#include <hip/hip_runtime.h>

// GraphSAGE 2-layer, N=50000, E=800000, D=128.
// R7: slice-major (chunk-contiguous) feature layout for the XCD-sharded
// gather. R6's slices were 256B-strided -> L2 set-index conflicts capped
// effective capacity at ~1MB (45% miss). Now xs/hbs/aggs are [4][N][32]
// (each chunk slice = contiguous 3.2MB, fits a 4MB XCD L2 using all sets).
// chunk = blockIdx&3 rides the blockIdx%8->XCD round-robin.
// Rest unchanged (counting-sort CSR, MFMA dual-GEMM).

#define D 128
#define NBITS 7
#define BNODES 128   // nodes per bucket
#define GA 64        // phase A/B block count
#define NPG 16       // nodes per block in sharded aggregate
typedef unsigned short u16;
typedef unsigned u32;
typedef unsigned long long u64;
typedef short bf16x8 __attribute__((ext_vector_type(8)));
typedef float f32x4 __attribute__((ext_vector_type(4)));

__device__ __forceinline__ u16 f2bf(float f) {
    union { float f; unsigned u; } x;
    x.f = f;
    unsigned r = x.u + 0x7FFF + ((x.u >> 16) & 1);  // RNE
    return (u16)(r >> 16);
}
__device__ __forceinline__ float bf2f(u16 b) {
    union { unsigned u; float f; } x;
    x.u = ((unsigned)b) << 16;
    return x.f;
}

// ---------------- CSR build: two-level counting sort ----------------

__global__ __launch_bounds__(1024) void bucket_hist(const int* __restrict__ dst,
                                                    int* __restrict__ Gcounts,
                                                    int E, int NB, int chunk) {
    __shared__ int cnt[512];
    for (int i = threadIdx.x; i < NB; i += 1024) cnt[i] = 0;
    __syncthreads();
    int base = blockIdx.x * chunk;
    int end = base + chunk; if (end > E) end = E;
    for (int e = base + threadIdx.x; e < end; e += 1024)
        atomicAdd(&cnt[dst[e] >> NBITS], 1);
    __syncthreads();
    for (int b = threadIdx.x; b < NB; b += 1024)
        Gcounts[b * GA + blockIdx.x] = cnt[b];
}

__global__ __launch_bounds__(1024) void scan1_kernel(const int* __restrict__ in,
                                                     int* __restrict__ excl,
                                                     int* __restrict__ totals, int n) {
    int chunk = blockIdx.x;
    int i = chunk * 1024 + threadIdx.x;
    int v = (i < n) ? in[i] : 0;
    int lane = threadIdx.x & 63;
    int wid = threadIdx.x >> 6;
    int s = v;
    #pragma unroll
    for (int off = 1; off < 64; off <<= 1) {
        int t = __shfl_up(s, off);
        if (lane >= off) s += t;
    }
    __shared__ int wsum[16];
    if (lane == 63) wsum[wid] = s;
    __syncthreads();
    if (wid == 0) {
        int ws = (lane < 16) ? wsum[lane] : 0;
        #pragma unroll
        for (int off = 1; off < 16; off <<= 1) {
            int t = __shfl_up(ws, off);
            if (lane >= off) ws += t;
        }
        if (lane < 16) wsum[lane] = ws;
    }
    __syncthreads();
    int wave_off = (wid > 0) ? wsum[wid - 1] : 0;
    int incl = s + wave_off;
    if (i < n) excl[i] = incl - v;
    if (threadIdx.x == 1023) totals[chunk] = incl;
}

__global__ __launch_bounds__(1024) void scan_add(int* __restrict__ Sc,
                                                 const int* __restrict__ totals, int n) {
    int chunk = blockIdx.x;
    int i = chunk * 1024 + threadIdx.x;
    int off = 0;
    for (int j = 0; j < chunk; ++j) off += totals[j];
    if (i < n) Sc[i] += off;
}

__global__ __launch_bounds__(1024) void bucket_scatter(const int* __restrict__ src,
                                                       const int* __restrict__ dst,
                                                       const int* __restrict__ Sc,
                                                       u32* __restrict__ Ebuck,
                                                       int E, int NB, int chunk) {
    __shared__ int cur[512];
    for (int b = threadIdx.x; b < NB; b += 1024) cur[b] = Sc[b * GA + blockIdx.x];
    __syncthreads();
    int base = blockIdx.x * chunk;
    int end = base + chunk; if (end > E) end = E;
    for (int e = base + threadIdx.x; e < end; e += 1024) {
        int d = dst[e];
        int b = d >> NBITS;
        int pos = atomicAdd(&cur[b], 1);
        Ebuck[pos] = ((u32)(d & (BNODES - 1)) << 16) | (u32)src[e];
    }
}

__global__ __launch_bounds__(256) void bucket_sort_csr(u32* __restrict__ Ebuck,
                                                       const int* __restrict__ Sc,
                                                       int* __restrict__ row_ptr,
                                                       int E, int N, int NB) {
    __shared__ int hist[BNODES], excl[BNODES], cur[BNODES];
    __shared__ u16 sorted[8192];
    int b = blockIdx.x;
    int start = Sc[b * GA];
    int endv = (b + 1 < NB) ? Sc[(b + 1) * GA] : E;
    int cnt = endv - start;
    if (cnt > 8192) cnt = 8192;
    for (int i = threadIdx.x; i < BNODES; i += 256) hist[i] = 0;
    __syncthreads();
    for (int i = threadIdx.x; i < cnt; i += 256)
        atomicAdd(&hist[Ebuck[start + i] >> 16], 1);
    __syncthreads();
    if (threadIdx.x == 0) {
        int run = 0;
        for (int i = 0; i < BNODES; ++i) { excl[i] = run; run += hist[i]; }
    }
    __syncthreads();
    for (int i = threadIdx.x; i < BNODES; i += 256) {
        cur[i] = excl[i];
        int g = b * BNODES + i;
        if (g <= N) row_ptr[g] = start + excl[i];
    }
    __syncthreads();
    for (int i = threadIdx.x; i < cnt; i += 256) {
        u32 r = Ebuck[start + i];
        int pos = atomicAdd(&cur[r >> 16], 1);
        sorted[pos] = (u16)(r & 0xFFFF);
    }
    __syncthreads();
    for (int i = threadIdx.x; i < cnt; i += 256)
        ((int*)Ebuck)[start + i] = (int)sorted[i];   // csr == Ebuck alias
}

// ---------------- fp32 -> bf16 converts (slice-major output) ----------------
// out layout: xs[c][node][32], c = chunk 0..3. SL = N*32 elems per slice.
__global__ void f32_to_slices_kernel(const float* __restrict__ in, u16* __restrict__ out,
                                     int n4, size_t SL) {
    int i = blockIdx.x * 256 + threadIdx.x;
    if (i < n4) {
        int node = i >> 5;          // 32 quads per node
        int q = i & 31;             // feature quad
        int c = q >> 3;             // chunk
        int wi = (q & 7) * 4;       // within-slice feature
        float4 v = *(const float4*)&in[i * 4];
        ushort4 o;
        o.x = f2bf(v.x); o.y = f2bf(v.y); o.z = f2bf(v.z); o.w = f2bf(v.w);
        *(ushort4*)&out[c * SL + (size_t)node * 32 + wi] = o;
    }
}

__global__ void convert_weights(const float* __restrict__ w0, const float* __restrict__ w1,
                                const float* __restrict__ w2, const float* __restrict__ w3,
                                u16* __restrict__ o0, u16* __restrict__ o1,
                                u16* __restrict__ o2, u16* __restrict__ o3) {
    int i = blockIdx.x * 256 + threadIdx.x;
    const int q = D * D / 4;  // 4096
    int m = i / q, j = i % q;
    const float* in = (m == 0) ? w0 : (m == 1) ? w1 : (m == 2) ? w2 : w3;
    u16* out = (m == 0) ? o0 : (m == 1) ? o1 : (m == 2) ? o2 : o3;
    float4 v = *(const float4*)&in[j * 4];
    ushort4 o;
    o.x = f2bf(v.x); o.y = f2bf(v.y); o.z = f2bf(v.z); o.w = f2bf(v.w);
    *(ushort4*)&out[j * 4] = o;
}

// ---------------- XCD-sharded mean aggregation (contiguous slices) ----------
// chunk = blockIdx&3; slice xs[c] is contiguous 3.2MB -> L2-resident.
// Wave: lane = slot(8)*8 + featquad(8); lane loads ushort4 (8B); 16 edges in
// flight; shfl_xor(8/16/32) reduces slots; slot-0 lanes store 64B/node.
__global__ __launch_bounds__(256) void aggregate_sharded(const u16* __restrict__ xs,
                                                         const int* __restrict__ row_ptr,
                                                         const int* __restrict__ csr,
                                                         u16* __restrict__ aggs,
                                                         int n, size_t SL) {
    const int chunk = blockIdx.x & 3;
    const int grp = blockIdx.x >> 2;
    const int wave = threadIdx.x >> 6;
    const int lane = threadIdx.x & 63;
    const int g = lane >> 3;               // edge slot 0..7
    const int f = lane & 7;                // feature quad 0..7
    const u16* xsl = xs + chunk * SL;
    u16* asl = aggs + chunk * SL;
    const int wi = f * 4;

    #pragma unroll
    for (int i = 0; i < NPG / 4; ++i) {
        int node = grp * NPG + wave * (NPG / 4) + i;
        if (node >= n) return;
        int begin = row_ptr[node], end = row_ptr[node + 1];
        float a0 = 0.f, a1 = 0.f, a2 = 0.f, a3 = 0.f;
        int j = begin + g;
        for (; j + 8 < end; j += 16) {   // 16 edges per round (2 per slot)
            int s0 = __builtin_nontemporal_load(&csr[j]);
            int s1 = __builtin_nontemporal_load(&csr[j + 8]);
            ushort4 v0 = *(const ushort4*)&xsl[(size_t)s0 * 32 + wi];
            ushort4 v1 = *(const ushort4*)&xsl[(size_t)s1 * 32 + wi];
            a0 += bf2f(v0.x) + bf2f(v1.x);
            a1 += bf2f(v0.y) + bf2f(v1.y);
            a2 += bf2f(v0.z) + bf2f(v1.z);
            a3 += bf2f(v0.w) + bf2f(v1.w);
        }
        if (j < end) {
            int s0 = __builtin_nontemporal_load(&csr[j]);
            ushort4 v0 = *(const ushort4*)&xsl[(size_t)s0 * 32 + wi];
            a0 += bf2f(v0.x); a1 += bf2f(v0.y); a2 += bf2f(v0.z); a3 += bf2f(v0.w);
        }
        a0 += __shfl_xor(a0, 8);  a1 += __shfl_xor(a1, 8);
        a2 += __shfl_xor(a2, 8);  a3 += __shfl_xor(a3, 8);
        a0 += __shfl_xor(a0, 16); a1 += __shfl_xor(a1, 16);
        a2 += __shfl_xor(a2, 16); a3 += __shfl_xor(a3, 16);
        a0 += __shfl_xor(a0, 32); a1 += __shfl_xor(a1, 32);
        a2 += __shfl_xor(a2, 32); a3 += __shfl_xor(a3, 32);
        if (g == 0) {
            int d = end - begin;
            if (d < 1) d = 1;
            float inv = 1.0f / (float)d;
            u64 o = (u64)f2bf(a0 * inv)
                  | ((u64)f2bf(a1 * inv) << 16)
                  | ((u64)f2bf(a2 * inv) << 32)
                  | ((u64)f2bf(a3 * inv) << 48);
            __builtin_nontemporal_store(o, (u64*)&asl[(size_t)node * 32 + wi]);
        }
    }
}

// ---------------- dual-GEMM via MFMA (slice-major A inputs) ----------------
#define LSTR 136

__global__ __launch_bounds__(256) void gemm_mfma(const u16* __restrict__ Aroot,
                                                 const u16* __restrict__ Wr,
                                                 const u16* __restrict__ Agg,
                                                 const u16* __restrict__ Wl,
                                                 const float* __restrict__ bias,
                                                 void* __restrict__ out,
                                                 int n, size_t SL, int mode) {
    __shared__ __align__(16) u16 Lr[64 * LSTR];
    __shared__ __align__(16) u16 Lg[64 * LSTR];
    const int tid = threadIdx.x;
    const int n0 = blockIdx.x * 64;

    // stage 64 rows x 128 feats from slice-major: feature group c4*8.. is
    // 16B contiguous inside chunk c4>>2 at within-offset (c4&3)*8.
    {
        int row = tid >> 4;
        int c4 = tid & 15;
        size_t soff = (size_t)(c4 >> 2) * SL + (size_t)(c4 & 3) * 8;
        int ldc = c4 * 8;
        #pragma unroll
        for (int p = 0; p < 4; ++p) {
            int r = p * 16 + row;
            int g = n0 + r;
            float4 vr = make_float4(0.f, 0.f, 0.f, 0.f);
            float4 vg = make_float4(0.f, 0.f, 0.f, 0.f);
            if (g < n) {
                vr = *(const float4*)&Aroot[soff + (size_t)g * 32];
                vg = *(const float4*)&Agg[soff + (size_t)g * 32];
            }
            *(float4*)&Lr[r * LSTR + ldc] = vr;
            *(float4*)&Lg[r * LSTR + ldc] = vg;
        }
    }

    const int wave = tid >> 6;
    const int lane = tid & 63;
    const int quad = lane >> 4;
    const int l16 = lane & 15;

    bf16x8 wr[2][4], wl[2][4];
    #pragma unroll
    for (int mt = 0; mt < 2; ++mt) {
        int jrow = wave * 32 + mt * 16 + l16;
        #pragma unroll
        for (int kb = 0; kb < 4; ++kb) {
            wr[mt][kb] = *(const bf16x8*)&Wr[jrow * D + kb * 32 + quad * 8];
            wl[mt][kb] = *(const bf16x8*)&Wl[jrow * D + kb * 32 + quad * 8];
        }
    }

    __syncthreads();

    f32x4 acc[4][2];
    #pragma unroll
    for (int it = 0; it < 4; ++it)
        #pragma unroll
        for (int mt = 0; mt < 2; ++mt)
            acc[it][mt] = (f32x4){0.f, 0.f, 0.f, 0.f};

    #pragma unroll
    for (int it = 0; it < 4; ++it) {
        int base = (it * 16 + l16) * LSTR + quad * 8;
        #pragma unroll
        for (int kb = 0; kb < 4; ++kb) {
            bf16x8 bx = *(const bf16x8*)&Lr[base + kb * 32];
            bf16x8 bg = *(const bf16x8*)&Lg[base + kb * 32];
            #pragma unroll
            for (int mt = 0; mt < 2; ++mt) {
                acc[it][mt] = __builtin_amdgcn_mfma_f32_16x16x32_bf16(wr[mt][kb], bx, acc[it][mt], 0, 0, 0);
                acc[it][mt] = __builtin_amdgcn_mfma_f32_16x16x32_bf16(wl[mt][kb], bg, acc[it][mt], 0, 0, 0);
            }
        }
    }

    // epilogue. mode1: relu + bf16 slice-major (chunk = wave, within = mt*16+quad*4)
    #pragma unroll
    for (int it = 0; it < 4; ++it) {
        int i = n0 + it * 16 + l16;
        if (i < n) {
            #pragma unroll
            for (int mt = 0; mt < 2; ++mt) {
                int j0 = wave * 32 + mt * 16 + quad * 4;
                float4 bv = *(const float4*)&bias[j0];
                float o0 = acc[it][mt][0] + bv.x;
                float o1 = acc[it][mt][1] + bv.y;
                float o2 = acc[it][mt][2] + bv.z;
                float o3 = acc[it][mt][3] + bv.w;
                if (mode) {
                    o0 = fmaxf(o0, 0.f); o1 = fmaxf(o1, 0.f);
                    o2 = fmaxf(o2, 0.f); o3 = fmaxf(o3, 0.f);
                    ushort4 ob;
                    ob.x = f2bf(o0); ob.y = f2bf(o1); ob.z = f2bf(o2); ob.w = f2bf(o3);
                    *(ushort4*)&((u16*)out)[(size_t)wave * SL + (size_t)i * 32 + mt * 16 + quad * 4] = ob;
                } else {
                    float4 of = make_float4(o0, o1, o2, o3);
                    *(float4*)&((float*)out)[(size_t)i * D + j0] = of;
                }
            }
        }
    }
}

// ---------------- launch ----------------

extern "C" void kernel_launch(void* const* d_in, const int* in_sizes, int n_in,
                              void* d_out, int out_size, void* d_ws, size_t ws_size,
                              hipStream_t stream) {
    const float* x = (const float*)d_in[0];
    const int* edge = (const int*)d_in[1];
    const float* Wl0 = (const float*)d_in[2];
    const float* Wr0 = (const float*)d_in[3];
    const float* b0 = (const float*)d_in[4];
    const float* Wl1 = (const float*)d_in[5];
    const float* Wr1 = (const float*)d_in[6];
    const float* b1 = (const float*)d_in[7];

    const int N = in_sizes[0] / D;
    const int E = in_sizes[1] / 2;
    const int* src = edge;
    const int* dst = edge + E;
    const size_t SL = (size_t)N * 32;   // elems per feature slice

    char* ws = (char*)d_ws;
    size_t off = 0;
    auto alloc = [&](size_t bytes) {
        char* p = ws + off;
        off += (bytes + 255) & ~(size_t)255;
        return p;
    };
    int* row_ptr = (int*)alloc((size_t)(N + 1) * 4);
    u32* Ebuck = (u32*)alloc((size_t)E * 4);          // becomes csr in-place
    u16* xs = (u16*)alloc((size_t)N * D * 2);         // slice-major x
    u16* hbs = (u16*)alloc((size_t)N * D * 2);        // slice-major h
    u16* aggs = (u16*)alloc((size_t)N * D * 2);       // slice-major agg
    u16* Wl0b = (u16*)alloc((size_t)D * D * 2);
    u16* Wr0b = (u16*)alloc((size_t)D * D * 2);
    u16* Wl1b = (u16*)alloc((size_t)D * D * 2);
    u16* Wr1b = (u16*)alloc((size_t)D * D * 2);
    const int NB = (N + BNODES - 1) / BNODES;
    const int scanN = NB * GA;
    int* Gcounts = (int*)aggs;   // scan scratch overlaps aggs (dead until agg)
    int* Sc = Gcounts + scanN;
    int* totals = Sc + scanN;

    (void)ws_size; (void)n_in; (void)out_size;

    const int chunk = (E + GA - 1) / GA;
    const int scanBlocks = (scanN + 1023) / 1024;

    // CSR build
    bucket_hist<<<GA, 1024, 0, stream>>>(dst, Gcounts, E, NB, chunk);
    scan1_kernel<<<scanBlocks, 1024, 0, stream>>>(Gcounts, Sc, totals, scanN);
    scan_add<<<scanBlocks, 1024, 0, stream>>>(Sc, totals, scanN);
    bucket_scatter<<<GA, 1024, 0, stream>>>(src, dst, Sc, Ebuck, E, NB, chunk);
    bucket_sort_csr<<<NB, 256, 0, stream>>>(Ebuck, Sc, row_ptr, E, N, NB);
    const int* csr = (const int*)Ebuck;

    // converts
    int xQuads = N * D / 4;
    f32_to_slices_kernel<<<(xQuads + 255) / 256, 256, 0, stream>>>(x, xs, xQuads, SL);
    convert_weights<<<(4 * D * D / 4 + 255) / 256, 256, 0, stream>>>(
        Wl0, Wr0, Wl1, Wr1, Wl0b, Wr0b, Wl1b, Wr1b);

    int aggBlocks = 4 * ((N + NPG - 1) / NPG);
    int gemmBlocks = (N + 63) / 64;

    // layer 0
    aggregate_sharded<<<aggBlocks, 256, 0, stream>>>(xs, row_ptr, csr, aggs, N, SL);
    gemm_mfma<<<gemmBlocks, 256, 0, stream>>>(xs, Wr0b, aggs, Wl0b, b0, hbs, N, SL, 1);
    // layer 1
    aggregate_sharded<<<aggBlocks, 256, 0, stream>>>(hbs, row_ptr, csr, aggs, N, SL);
    gemm_mfma<<<gemmBlocks, 256, 0, stream>>>(hbs, Wr1b, aggs, Wl1b, b1, d_out, N, SL, 0);
}